// Round 5
// baseline (1322.839 us; speedup 1.0000x reference)
//
#include <hip/hip_runtime.h>

// ColorQuantizer: out[b,c,h,w] = palette[argmin_i dist(processed(x[b,:,h,w]), palette_i)][c]
// processed = relu(x@W1 + b1) @ W2 + b2   (fp32, replicate reference op order)
//
// R5: R4's exact math (validated absmax 0.0), restructured for occupancy.
// R4 was latency-bound: VGPR 144 -> 3 waves/SIMD, VALUBusy 58%. Fix: process
// the thread's 8 pixels as two sequential halves of 4 (rolled h-loop) so only
// 4 pixels of X/P state are live at once; pack per-pixel argmin into 4-bit
// nibbles of one unsigned. Weights stored interleaved in LDS (32 B per hidden
// unit -> 2x ds_read_b128 per j instead of 7 scalar reads).
// Tie ladder (unchanged from R4, exact):
//   hot loop: (min, second-min, argmin) of clamped sq   [sqrt-free]
//   prefilter pv <= bd*(1+4e-6); then 2 sqrts; true d-tie -> rolled rescan.

#define PV(v) ((float)(v)/255.0f*2.0f-1.0f)
#define ROWF(r,g,c) {PV(r), PV(g), PV(c)}

// Runtime-indexed palette (global .rodata): epilogue gather + cold rescan.
__device__ const float PALG[16][3] = {
  ROWF(0,0,0),       ROWF(255,255,255), ROWF(255,0,0),     ROWF(0,255,0),
  ROWF(0,0,255),     ROWF(255,255,0),   ROWF(255,0,255),   ROWF(0,255,255),
  ROWF(128,128,128), ROWF(128,0,0),     ROWF(0,128,0),     ROWF(0,0,128),
  ROWF(128,128,0),   ROWF(128,0,128),   ROWF(0,128,128),   ROWF(192,192,192)
};

// Compile-time palette for the hot unrolled loop (folds to immediates).
constexpr int COLI[16][3] = {
  {0,0,0},{255,255,255},{255,0,0},{0,255,0},{0,0,255},{255,255,0},
  {255,0,255},{0,255,255},{128,128,128},{128,0,0},{0,128,0},{0,0,128},
  {128,128,0},{128,0,128},{0,128,128},{192,192,192}
};
constexpr float PVF(int v){ return (float)v/255.0f*2.0f-1.0f; }
constexpr float PXc(int i){ return PVF(COLI[i][0]); }
constexpr float PYc(int i){ return PVF(COLI[i][1]); }
constexpr float PZc(int i){ return PVF(COLI[i][2]); }
// sum(PALETTE*PALETTE, axis=-1), reference reduce order: (x*x + y*y) + z*z
constexpr float PSQc(int i){ return (PXc(i)*PXc(i) + PYc(i)*PYc(i)) + PZc(i)*PZc(i); }

constexpr int HW    = 512*512;
constexpr int PXT   = 8;          // pixels per thread (two halves of 4)
constexpr int BLOCK = 256;

// Cold path: exact sqrt argmin, ROLLED, palette from memory.
// Executed only on true d-ties (expected handful of pixels per image).
static __device__ __forceinline__ int exact_rescan(float p0, float p1, float p2, float psq)
{
#pragma clang fp contract(off)
    float bd = 3.4e38f;
    int   bi = 0;
#pragma unroll 1
    for (int i = 0; i < 16; ++i) {
        const float cx = PALG[i][0], cy = PALG[i][1], cz = PALG[i][2];
        const float csq = (cx*cx + cy*cy) + cz*cz;          // == PSQc(i) bitwise
        float dot = __builtin_fmaf(p2, cz, __builtin_fmaf(p1, cy, p0*cx));
        float sq  = (psq - 2.0f*dot) + csq;
        float d   = sqrtf(fmaxf(sq, 0.0f));
        if (d < bd) { bd = d; bi = i; }
    }
    return bi;
}

__global__ __launch_bounds__(BLOCK, 4) void cq_kernel(
    const float* __restrict__ x,   const float* __restrict__ W1g,
    const float* __restrict__ b1g, const float* __restrict__ W2g,
    const float* __restrict__ b2g, float* __restrict__ out)
{
#pragma clang fp contract(off)
    // Interleaved weight records: sw[j*8 + {0,1,2,3,4,5,6,7}] =
    //   W1[0][j], W1[1][j], W1[2][j], b1[j], W2[j][0], W2[j][1], W2[j][2], 0
    __shared__ float sw[32*8];
    __shared__ float sb2s[3];

    const int t = threadIdx.x;
    {
        const int j = t >> 3, c = t & 7;
        float v;
        if      (c < 3)  v = W1g[c*32 + j];
        else if (c == 3) v = b1g[j];
        else if (c < 7)  v = W2g[j*3 + (c-4)];
        else             v = 0.0f;
        sw[t] = v;
        if (t < 3) sb2s[t] = b2g[t];
    }
    __syncthreads();

    const int pix = (blockIdx.x * BLOCK + t) * PXT;
    const int img = pix >> 18;                       // HW = 2^18
    const int hw  = pix & (HW - 1);
    const size_t base = (size_t)img * (size_t)(3*HW) + (size_t)hw;

    const float bz0 = sb2s[0], bz1 = sb2s[1], bz2 = sb2s[2];

    unsigned bestpack = 0;   // 4 bits per pixel

#pragma unroll 1
    for (int h = 0; h < 2; ++h) {
        const size_t hb = base + 4*h;
        const float4 a  = *(const float4*)(x + hb);
        const float4 c4 = *(const float4*)(x + hb + HW);
        const float4 e  = *(const float4*)(x + hb + 2*HW);
        float X0[4] = {a.x, a.y, a.z, a.w};
        float X1[4] = {c4.x, c4.y, c4.z, c4.w};
        float X2[4] = {e.x, e.y, e.z, e.w};
        float P0[4] = {0.f,0.f,0.f,0.f};
        float P1[4] = {0.f,0.f,0.f,0.f};
        float P2[4] = {0.f,0.f,0.f,0.f};

        // Fused MLP: h = relu(fma(x2,w2,fma(x1,w1,x0*w0)) + b1_j); P_c += h*W2[j][c]
#pragma unroll
        for (int j = 0; j < 32; ++j) {
            const float4 wa = *(const float4*)(&sw[j*8]);     // w0,w1,w2,b1
            const float4 wb = *(const float4*)(&sw[j*8+4]);   // u0,u1,u2,-
#pragma unroll
            for (int k = 0; k < 4; ++k) {
                float hh = __builtin_fmaf(X2[k], wa.z, __builtin_fmaf(X1[k], wa.y, X0[k]*wa.x));
                hh = hh + wa.w;
                hh = fmaxf(hh, 0.0f);
                P0[k] = __builtin_fmaf(hh, wb.x, P0[k]);
                P1[k] = __builtin_fmaf(hh, wb.y, P1[k]);
                P2[k] = __builtin_fmaf(hh, wb.z, P2[k]);
            }
        }

#pragma unroll
        for (int k = 0; k < 4; ++k) {
            const float p0 = P0[k] + bz0;
            const float p1 = P1[k] + bz1;
            const float p2 = P2[k] + bz2;
            const float psq = (p0*p0 + p1*p1) + p2*p2;   // reference reduce order

            float bd = 3.4e38f;     // min clamped sq
            float pv = 3.4e38f;     // second-min clamped sq
            int   bi = 0;
#pragma unroll
            for (int i = 0; i < 16; ++i) {
                float dot = __builtin_fmaf(p2, PZc(i), __builtin_fmaf(p1, PYc(i), p0*PXc(i)));
                // 2*dot exact (pow2), so fma(dot,-2,psq) == (psq - 2.0f*dot) bitwise
                float sq  = __builtin_fmaf(dot, -2.0f, psq) + PSQc(i);
                sq = fmaxf(sq, 0.0f);                    // ref clamps before sqrt
                bool c = sq < bd;                        // strict: first occurrence wins
                float m = fminf(sq, pv);
                pv = c ? bd : m;
                bi = c ? i  : bi;
                bd = c ? sq : bd;
            }
            // d-tie possible only within sqrt's rounding-collision window.
            if (__builtin_expect(pv <= bd * 1.000004f, 0)) {
                if (sqrtf(pv) == sqrtf(bd))              // sandwich: differ => no tie
                    bi = exact_rescan(p0, p1, p2, psq);
            }
            bestpack |= (unsigned)bi << (4*(4*h + k));
        }
    }

    int b[PXT];
#pragma unroll
    for (int k = 0; k < PXT; ++k) b[k] = (bestpack >> (4*k)) & 15;

    float* op = out + base;   // output shares the [b][c][hw] layout
    float4 o;
    o = make_float4(PALG[b[0]][0], PALG[b[1]][0], PALG[b[2]][0], PALG[b[3]][0]);
    *(float4*)(op) = o;
    o = make_float4(PALG[b[4]][0], PALG[b[5]][0], PALG[b[6]][0], PALG[b[7]][0]);
    *(float4*)(op + 4) = o;
    o = make_float4(PALG[b[0]][1], PALG[b[1]][1], PALG[b[2]][1], PALG[b[3]][1]);
    *(float4*)(op + HW) = o;
    o = make_float4(PALG[b[4]][1], PALG[b[5]][1], PALG[b[6]][1], PALG[b[7]][1]);
    *(float4*)(op + HW + 4) = o;
    o = make_float4(PALG[b[0]][2], PALG[b[1]][2], PALG[b[2]][2], PALG[b[3]][2]);
    *(float4*)(op + 2*HW) = o;
    o = make_float4(PALG[b[4]][2], PALG[b[5]][2], PALG[b[6]][2], PALG[b[7]][2]);
    *(float4*)(op + 2*HW + 4) = o;
}

extern "C" void kernel_launch(void* const* d_in, const int* in_sizes, int n_in,
                              void* d_out, int out_size, void* d_ws, size_t ws_size,
                              hipStream_t stream) {
    const float* x  = (const float*)d_in[0];
    const float* W1 = (const float*)d_in[1];
    const float* b1 = (const float*)d_in[2];
    const float* W2 = (const float*)d_in[3];
    const float* b2 = (const float*)d_in[4];
    float* outp = (float*)d_out;

    constexpr int NPIX = 32 * HW;                    // 8,388,608
    constexpr int GRID = NPIX / (BLOCK * PXT);       // 4096 blocks, exact
    hipLaunchKernelGGL(cq_kernel, dim3(GRID), dim3(BLOCK), 0, stream,
                       x, W1, b1, W2, b2, outp);
}

// Round 6
// 287.554 us; speedup vs baseline: 4.6003x; 4.6003x over previous
//
#include <hip/hip_runtime.h>

// ColorQuantizer: out[b,c,h,w] = palette[argmin_i dist(processed(x[b,:,h,w]), palette_i)][c]
// processed = relu(x@W1 + b1) @ W2 + b2   (fp32, replicate reference op order)
//
// R6: R4's exact math and flat structure (validated absmax 0.0, zero scratch),
// with PXT 8->4 to halve live register state (R4: VGPR 144 -> 3 waves/SIMD,
// VALUBusy 58% = latency-bound). No rolled loops, no launch-bounds floor
// (R5 lesson: rolled h-loop + waves floor -> LICM hoisted 256 floats of
// loop-invariant LDS weight loads -> 4.3 GB scratch storm).
// Weights in interleaved LDS records: 2x ds_read_b128 per hidden unit.
// Tie ladder (unchanged, exact):
//   hot loop: (min, second-min, argmin) of clamped sq   [sqrt-free]
//   prefilter pv <= bd*(1+4e-6); then 2 sqrts; true d-tie -> rolled rescan.

#define PV(v) ((float)(v)/255.0f*2.0f-1.0f)
#define ROWF(r,g,c) {PV(r), PV(g), PV(c)}

// Runtime-indexed palette (global .rodata): epilogue gather + cold rescan.
__device__ const float PALG[16][3] = {
  ROWF(0,0,0),       ROWF(255,255,255), ROWF(255,0,0),     ROWF(0,255,0),
  ROWF(0,0,255),     ROWF(255,255,0),   ROWF(255,0,255),   ROWF(0,255,255),
  ROWF(128,128,128), ROWF(128,0,0),     ROWF(0,128,0),     ROWF(0,0,128),
  ROWF(128,128,0),   ROWF(128,0,128),   ROWF(0,128,128),   ROWF(192,192,192)
};

// Compile-time palette for the hot unrolled loop (folds to immediates).
constexpr int COLI[16][3] = {
  {0,0,0},{255,255,255},{255,0,0},{0,255,0},{0,0,255},{255,255,0},
  {255,0,255},{0,255,255},{128,128,128},{128,0,0},{0,128,0},{0,0,128},
  {128,128,0},{128,0,128},{0,128,128},{192,192,192}
};
constexpr float PVF(int v){ return (float)v/255.0f*2.0f-1.0f; }
constexpr float PXc(int i){ return PVF(COLI[i][0]); }
constexpr float PYc(int i){ return PVF(COLI[i][1]); }
constexpr float PZc(int i){ return PVF(COLI[i][2]); }
// sum(PALETTE*PALETTE, axis=-1), reference reduce order: (x*x + y*y) + z*z
constexpr float PSQc(int i){ return (PXc(i)*PXc(i) + PYc(i)*PYc(i)) + PZc(i)*PZc(i); }

constexpr int HW    = 512*512;
constexpr int PXT   = 4;          // pixels per thread
constexpr int BLOCK = 256;

// Cold path: exact sqrt argmin, ROLLED, palette from memory.
// Executed only on true d-ties (expected handful of pixels per image).
static __device__ __forceinline__ int exact_rescan(float p0, float p1, float p2, float psq)
{
#pragma clang fp contract(off)
    float bd = 3.4e38f;
    int   bi = 0;
#pragma unroll 1
    for (int i = 0; i < 16; ++i) {
        const float cx = PALG[i][0], cy = PALG[i][1], cz = PALG[i][2];
        const float csq = (cx*cx + cy*cy) + cz*cz;          // == PSQc(i) bitwise
        float dot = __builtin_fmaf(p2, cz, __builtin_fmaf(p1, cy, p0*cx));
        float sq  = (psq - 2.0f*dot) + csq;
        float d   = sqrtf(fmaxf(sq, 0.0f));
        if (d < bd) { bd = d; bi = i; }
    }
    return bi;
}

__global__ __launch_bounds__(BLOCK) void cq_kernel(
    const float* __restrict__ x,   const float* __restrict__ W1g,
    const float* __restrict__ b1g, const float* __restrict__ W2g,
    const float* __restrict__ b2g, float* __restrict__ out)
{
#pragma clang fp contract(off)
    // Interleaved weight records: sw[j*8 + {0..7}] =
    //   W1[0][j], W1[1][j], W1[2][j], b1[j], W2[j][0], W2[j][1], W2[j][2], 0
    __shared__ float sw[32*8];
    __shared__ float sb2s[3];

    const int t = threadIdx.x;
    {
        const int j = t >> 3, c = t & 7;
        float v;
        if      (c < 3)  v = W1g[c*32 + j];
        else if (c == 3) v = b1g[j];
        else if (c < 7)  v = W2g[j*3 + (c-4)];
        else             v = 0.0f;
        sw[t] = v;
        if (t < 3) sb2s[t] = b2g[t];
    }
    __syncthreads();

    const int pix = (blockIdx.x * BLOCK + t) * PXT;
    const int img = pix >> 18;                       // HW = 2^18
    const int hw  = pix & (HW - 1);
    const size_t base = (size_t)img * (size_t)(3*HW) + (size_t)hw;

    const float4 a  = *(const float4*)(x + base);
    const float4 c4 = *(const float4*)(x + base + HW);
    const float4 e  = *(const float4*)(x + base + 2*HW);
    float X0[PXT] = {a.x, a.y, a.z, a.w};
    float X1[PXT] = {c4.x, c4.y, c4.z, c4.w};
    float X2[PXT] = {e.x, e.y, e.z, e.w};

    float P0[PXT] = {0.f,0.f,0.f,0.f};
    float P1[PXT] = {0.f,0.f,0.f,0.f};
    float P2[PXT] = {0.f,0.f,0.f,0.f};

    // Fused MLP: h = relu(fma(x2,w2,fma(x1,w1,x0*w0)) + b1_j); P_c += h*W2[j][c]
#pragma unroll
    for (int j = 0; j < 32; ++j) {
        const float4 wa = *(const float4*)(&sw[j*8]);     // w0,w1,w2,b1
        const float4 wb = *(const float4*)(&sw[j*8+4]);   // u0,u1,u2,-
#pragma unroll
        for (int k = 0; k < PXT; ++k) {
            float hh = __builtin_fmaf(X2[k], wa.z, __builtin_fmaf(X1[k], wa.y, X0[k]*wa.x));
            hh = hh + wa.w;
            hh = fmaxf(hh, 0.0f);
            P0[k] = __builtin_fmaf(hh, wb.x, P0[k]);
            P1[k] = __builtin_fmaf(hh, wb.y, P1[k]);
            P2[k] = __builtin_fmaf(hh, wb.z, P2[k]);
        }
    }

    const float bz0 = sb2s[0], bz1 = sb2s[1], bz2 = sb2s[2];

    int best[PXT];
#pragma unroll
    for (int k = 0; k < PXT; ++k) {
        const float p0 = P0[k] + bz0;
        const float p1 = P1[k] + bz1;
        const float p2 = P2[k] + bz2;
        const float psq = (p0*p0 + p1*p1) + p2*p2;   // reference reduce order

        float bd = 3.4e38f;     // min clamped sq
        float pv = 3.4e38f;     // second-min clamped sq
        int   bi = 0;
#pragma unroll
        for (int i = 0; i < 16; ++i) {
            float dot = __builtin_fmaf(p2, PZc(i), __builtin_fmaf(p1, PYc(i), p0*PXc(i)));
            // 2*dot exact (pow2), so fma(dot,-2,psq) == (psq - 2.0f*dot) bitwise
            float sq  = __builtin_fmaf(dot, -2.0f, psq) + PSQc(i);
            sq = fmaxf(sq, 0.0f);                    // ref clamps before sqrt
            bool c = sq < bd;                        // strict: first occurrence wins
            float m = fminf(sq, pv);
            pv = c ? bd : m;
            bi = c ? i  : bi;
            bd = c ? sq : bd;
        }
        // d-tie possible only within sqrt's rounding-collision window.
        if (__builtin_expect(pv <= bd * 1.000004f, 0)) {
            if (sqrtf(pv) == sqrtf(bd))              // sandwich: differ => no tie
                bi = exact_rescan(p0, p1, p2, psq);
        }
        best[k] = bi;
    }

    float* op = out + base;   // output shares the [b][c][hw] layout
    *(float4*)(op)        = make_float4(PALG[best[0]][0], PALG[best[1]][0], PALG[best[2]][0], PALG[best[3]][0]);
    *(float4*)(op + HW)   = make_float4(PALG[best[0]][1], PALG[best[1]][1], PALG[best[2]][1], PALG[best[3]][1]);
    *(float4*)(op + 2*HW) = make_float4(PALG[best[0]][2], PALG[best[1]][2], PALG[best[2]][2], PALG[best[3]][2]);
}

extern "C" void kernel_launch(void* const* d_in, const int* in_sizes, int n_in,
                              void* d_out, int out_size, void* d_ws, size_t ws_size,
                              hipStream_t stream) {
    const float* x  = (const float*)d_in[0];
    const float* W1 = (const float*)d_in[1];
    const float* b1 = (const float*)d_in[2];
    const float* W2 = (const float*)d_in[3];
    const float* b2 = (const float*)d_in[4];
    float* outp = (float*)d_out;

    constexpr int NPIX = 32 * HW;                    // 8,388,608
    constexpr int GRID = NPIX / (BLOCK * PXT);       // 8192 blocks, exact
    hipLaunchKernelGGL(cq_kernel, dim3(GRID), dim3(BLOCK), 0, stream,
                       x, W1, b1, W2, b2, outp);
}